// Round 4
// baseline (118.729 us; speedup 1.0000x reference)
//
#include <hip/hip_runtime.h>
#include <hip/hip_cooperative_groups.h>

namespace cg = cooperative_groups;

// VQ-VAE codebook forward, B=8,C=64,H=64,W=64, K=8192, D=64.
// Reference quirk: the cross term is a SCALAR, so argmin over k is independent
// of n: idx[n] == argmin_k |book_k|^2 for all n.
// Outputs (concatenated float32):
//   [0 .. 2097151]      z_q permuted to [B,W,C,H]: out[b,w,c,h] = e[w], e=book[kmin]
//   [2097152..2129919]  idx: 32768 x float(kmin)
//   [2129920]           loss = 1.25 * mean((e[w] - in[b,c,h,w])^2)
//
// R7: single cooperative kernel. Post-mortems: R4 (+16us) = device fence with
// 8MB dirty L2; R5/R6 (both ~73us, two different 2-dispatch structures) =
// per-kernel node overhead + gaps dominate, work-level edits are sub-noise.
// Last untested structural lever: ONE kernel node, grid.sync() between the
// kmin-independent phase (book argmin + in column-stats, 133KB of partials)
// and the dependent phase (z_q/idx stream + analytic loss). The grid barrier
// fires while L2 holds only ~133KB dirty -- the R4 failure mode (flush under
// 8MB dirty) cannot occur. Loss algebra identical to the verified R6 path:
// sum(e[w]-x)^2 = Sum(x^2) - 2*sum_w e_w*S_w + 32768*sum_w e_w^2 (fp64 folds,
// absmax was 0.0). z_q/idx bit-exact pure copies.
// Fallback: if this lands >= 73us, revert to the 3-kernel R3 (67.6us) and
// declare the fill-dominated floor.
// Note: ~42 us of dur_us is the harness's 256 MB d_ws re-poison fill
// (6.2-6.5 TB/s in the profile) -- outside our control.

#define NTOT  2097152   // 8*64*64*64
#define NIDX  32768
#define NBLK  512       // 512 blocks x 256 thr = 2 blocks/CU, co-resident

// ws layout: [0    .. 4095]   512 x u64 per-block argmin keys
//            [4096 .. 6143]   512 x f32 per-block sum(x^2) partials
//            [8192 .. 139263] 512 x 16 float4 per-block S_w partials

__global__ __launch_bounds__(256) void kFused(const float* __restrict__ in,
                                              const float* __restrict__ book,
                                              float* __restrict__ out,
                                              unsigned long long* __restrict__ ws_keys,
                                              float* __restrict__ ws_sin2,
                                              float4* __restrict__ ws_S) {
    const int t    = threadIdx.x;
    const int b    = blockIdx.x;
    const int lane = t & 63, wid = t >> 6;

    // ================= phase 1: kmin-independent work =================
    // issue ALL global loads up front (book + in) for latency overlap
    const int row = b * 16 + (t >> 4);            // book row, 16 rows/block
    const int c4  = t & 15;                       // float4 column within row
    const float4 bv = ((const float4*)book)[row * 16 + c4];   // coalesced

    float4 z[4];
    #pragma unroll
    for (int it = 0; it < 4; ++it)
        z[it] = ((const float4*)in)[b * 256 + t + it * (NBLK * 256)];

    // book |row|^2 argmin (verified R3 k1 arithmetic)
    float s = bv.x * bv.x + bv.y * bv.y + bv.z * bv.z + bv.w * bv.w;
    s += __shfl_down(s, 8, 16);
    s += __shfl_down(s, 4, 16);
    s += __shfl_down(s, 2, 16);
    s += __shfl_down(s, 1, 16);

    __shared__ unsigned long long keys[16];
    if (c4 == 0) {
        // positive-float bits are monotone as uint -> u64 min gives min norm,
        // ties broken to LOWEST row (jnp.argmin semantics).
        keys[t >> 4] = ((unsigned long long)__float_as_uint(s) << 32)
                     | (unsigned int)row;
    }

    // in statistics: scalar sum(x^2) + per-w column sums.
    // float4 index i = b*256 + t + it*131072; 256*b and 131072 are multiples
    // of 16, so i mod 16 == t mod 16: this thread always covers
    // w = 4*(t&15)..+3 -> its S-partial is one float4.
    float4 sv = make_float4(0.f, 0.f, 0.f, 0.f);
    float  s2 = 0.f;
    #pragma unroll
    for (int it = 0; it < 4; ++it) {
        sv.x += z[it].x; sv.y += z[it].y; sv.z += z[it].z; sv.w += z[it].w;
        s2 += z[it].x * z[it].x + z[it].y * z[it].y
            + z[it].z * z[it].z + z[it].w * z[it].w;
    }
    sv.x += __shfl_down(sv.x, 32, 64); sv.y += __shfl_down(sv.y, 32, 64);
    sv.z += __shfl_down(sv.z, 32, 64); sv.w += __shfl_down(sv.w, 32, 64);
    sv.x += __shfl_down(sv.x, 16, 64); sv.y += __shfl_down(sv.y, 16, 64);
    sv.z += __shfl_down(sv.z, 16, 64); sv.w += __shfl_down(sv.w, 16, 64);
    #pragma unroll
    for (int off = 32; off > 0; off >>= 1) s2 += __shfl_down(s2, off, 64);

    __shared__ float4 sWl[4][16];
    __shared__ float  s2l[4];
    if (lane < 16) sWl[wid][lane] = sv;
    if (lane == 0) s2l[wid] = s2;
    __syncthreads();

    if (t == 0) {
        unsigned long long k = keys[0];
        #pragma unroll
        for (int i = 1; i < 16; ++i) k = keys[i] < k ? keys[i] : k;
        ws_keys[b] = k;                           // plain store
    }
    if (t < 16) {
        float4 a = sWl[0][t], b4 = sWl[1][t], c = sWl[2][t], d = sWl[3][t];
        ws_S[b * 16 + t] = make_float4(a.x + b4.x + c.x + d.x,
                                       a.y + b4.y + c.y + d.y,
                                       a.z + b4.z + c.z + d.z,
                                       a.w + b4.w + c.w + d.w);
    }
    if (t == 16)
        ws_sin2[b] = s2l[0] + s2l[1] + s2l[2] + s2l[3];

    // ================= device-wide barrier =================
    // release/acquire handled by the runtime; only ~133KB dirty at this point
    cg::this_grid().sync();

    // ================= phase 2: kmin-dependent stream =================
    __shared__ unsigned long long skey;
    if (wid == 0) {
        unsigned long long key = ~0ULL;
        #pragma unroll
        for (int j = 0; j < NBLK / 64; ++j) {     // 8 strided loads per lane
            unsigned long long o = ws_keys[lane + j * 64];
            key = o < key ? o : key;
        }
        #pragma unroll
        for (int off = 32; off > 0; off >>= 1) {
            unsigned long long o = __shfl_down(key, off, 64);
            key = o < key ? o : key;
        }
        if (lane == 0) skey = key;
    }
    __syncthreads();
    const int kmin = (int)(skey & 0xFFFFFFFFu);
    const float* __restrict__ e = book + kmin * 64;   // LLC-hot broadcast

    const int tid = b * 256 + t;                      // 131072 threads

    // idx output: 32768 floats == float(kmin) (blocks 0..31)
    if (tid < NIDX / 4) {
        const float kf = (float)kmin;
        ((float4*)(out + NTOT))[tid] = make_float4(kf, kf, kf, kf);
    }

    // z_q out [B,W,C,H]: pure broadcast stream
    #pragma unroll
    for (int it = 0; it < 4; ++it) {
        const int i = tid + it * (NBLK * 256);        // float4 index
        const float ev = e[(i >> 10) & 63];           // o=4i -> e[(o>>12)&63]
        ((float4*)out)[i] = make_float4(ev, ev, ev, ev);
    }

    // block 0: analytic loss from phase-1 partials (LLC-hot)
    if (b == 0) {
        double a2 = 0.0, aes = 0.0, ae2 = 0.0;
        if (t < 16) {                                 // sum_w e_w^2
            const float4 ef = ((const float4*)e)[t];
            ae2 = (double)ef.x * ef.x + (double)ef.y * ef.y
                + (double)ef.z * ef.z + (double)ef.w * ef.w;
        }
        #pragma unroll
        for (int h = 0; h < 2; ++h) {                 // thread t: blocks t, t+256
            const int blk = t + h * 256;
            a2 += (double)ws_sin2[blk];
            #pragma unroll
            for (int j = 0; j < 16; ++j) {
                const float4 svp = ws_S[blk * 16 + j];
                const float4 ef  = ((const float4*)e)[j];
                aes += (double)svp.x * ef.x + (double)svp.y * ef.y
                     + (double)svp.z * ef.z + (double)svp.w * ef.w;
            }
        }
        #pragma unroll
        for (int off = 32; off > 0; off >>= 1) {
            a2  += __shfl_down(a2,  off, 64);
            aes += __shfl_down(aes, off, 64);
            ae2 += __shfl_down(ae2, off, 64);
        }
        __shared__ double sA[4], sE[4], sQ[4];
        if (lane == 0) { sA[wid] = a2; sE[wid] = aes; sQ[wid] = ae2; }
        __syncthreads();
        if (t == 0) {
            const double A2 = sA[0] + sA[1] + sA[2] + sA[3];
            const double ES = sE[0] + sE[1] + sE[2] + sE[3];
            const double E2 = sQ[0] + sQ[1] + sQ[2] + sQ[3];
            // sum (e[w]-x)^2 = sum x^2 - 2*sum_w e_w S_w + (N/64)*sum_w e_w^2
            const double loss = 1.25 * (A2 - 2.0 * ES + 32768.0 * E2)
                              / (double)NTOT;
            out[NTOT + NIDX] = (float)loss;
        }
    }
}

extern "C" void kernel_launch(void* const* d_in, const int* in_sizes, int n_in,
                              void* d_out, int out_size, void* d_ws, size_t ws_size,
                              hipStream_t stream) {
    const float* in   = (const float*)d_in[0];   // [8,64,64,64] fp32
    const float* book = (const float*)d_in[1];   // [8192,64] fp32
    float* out = (float*)d_out;

    unsigned long long* ws_keys = (unsigned long long*)d_ws;
    float*              ws_sin2 = (float*)((char*)d_ws + 4096);
    float4*             ws_S    = (float4*)((char*)d_ws + 8192);

    void* args[] = {(void*)&in, (void*)&book, (void*)&out,
                    (void*)&ws_keys, (void*)&ws_sin2, (void*)&ws_S};
    hipLaunchCooperativeKernel((const void*)kFused, dim3(NBLK), dim3(256),
                               args, 0, stream);
}

// Round 5
// 69.056 us; speedup vs baseline: 1.7193x; 1.7193x over previous
//
#include <hip/hip_runtime.h>

// VQ-VAE codebook forward, B=8,C=64,H=64,W=64, K=8192, D=64.
// Reference quirk: the cross term is a SCALAR, so argmin over k is independent
// of n: idx[n] == argmin_k |book_k|^2 for all n.
// Outputs (concatenated float32):
//   [0 .. 2097151]      z_q permuted to [B,W,C,H]: out[b,w,c,h] = e[w], e=book[kmin]
//   [2097152..2129919]  idx: 32768 x float(kmin)
//   [2129920]           loss = 1.25 * mean((e[w] - in[b,c,h,w])^2)
//
// R8: revert to the verified 3-dispatch R3 structure (67.6us). Structural
// post-mortems: R4 83.5us (device fence = L2 flush under 8MB dirty),
// R5 73.1us (sc1 drain + 512 same-address LLC atomics), R6 72.9us
// (2-dispatch algebraic split), R7 118.7us (cg::grid().sync() measured
// ~35us for 512 blocks -- the runtime barrier does the same per-XCD L2
// writeback/invalidate as R4, once per block wavefront). Conclusion: on
// gfx950 the KERNEL BOUNDARY is the cheapest cross-XCD coherence primitive;
// every intra-kernel alternative costs more than the dispatch it saves.
// Only retained micro-edit vs R3: k2 issues its 4 kmin-independent in-loads
// BEFORE the key resolve, hiding HBM latency under the resolve chain.
// Note: ~42 us of dur_us is the harness's 256 MB d_ws re-poison fill
// (6.2-6.6 TB/s in the profile) -- outside our control.

#define NTOT    2097152   // 8*64*64*64
#define NIDX    32768
#define K_ROWS  8192
#define K1_BLK  512       // 16 rows/block, 16 lanes (one float4) per row
#define K2_BLK  512
#define K2_ITER 4         // 524288 float4 tasks / (512*256)

// ws layout: [0 .. 4095] 512 x u64 per-block argmin keys
//            [4096 .. ]  512 x float loss partials

__global__ __launch_bounds__(256) void k1_argmin(const float* __restrict__ book,
                                                 unsigned long long* __restrict__ ws_keys) {
    const int t   = threadIdx.x;
    const int rIn = t >> 4;                       // row within block, 0..15
    const int c4  = t & 15;                       // float4 column
    const int row = blockIdx.x * 16 + rIn;

    const float4 v = ((const float4*)book)[row * 16 + c4];   // fully coalesced
    float s = v.x * v.x + v.y * v.y + v.z * v.z + v.w * v.w;
    // reduce across the 16 contiguous lanes of this row
    s += __shfl_down(s, 8, 16);
    s += __shfl_down(s, 4, 16);
    s += __shfl_down(s, 2, 16);
    s += __shfl_down(s, 1, 16);

    __shared__ unsigned long long keys[16];
    if (c4 == 0) {
        // positive-float bits are monotone as uint -> u64 min gives min norm,
        // ties broken to LOWEST row (jnp.argmin semantics).
        keys[rIn] = ((unsigned long long)__float_as_uint(s) << 32)
                  | (unsigned int)row;
    }
    __syncthreads();
    if (t == 0) {
        unsigned long long k = keys[0];
        #pragma unroll
        for (int i = 1; i < 16; ++i) k = keys[i] < k ? keys[i] : k;
        ws_keys[blockIdx.x] = k;                  // plain store, no atomic
    }
}

__global__ __launch_bounds__(256) void k2_main(const float* __restrict__ in,
                                               const float* __restrict__ book,
                                               float* __restrict__ out,
                                               const unsigned long long* __restrict__ ws_keys,
                                               float* __restrict__ ws_part) {
    const int lane = threadIdx.x & 63, wid = threadIdx.x >> 6;
    const int tid  = blockIdx.x * 256 + threadIdx.x;   // 131072 threads

    // ---- prefetch the 4 input float4s NOW: addresses are kmin-independent,
    //      so their HBM latency overlaps wave0's key resolve below ----
    float4 z[K2_ITER];
    #pragma unroll
    for (int it = 0; it < K2_ITER; ++it)
        z[it] = ((const float4*)in)[tid + it * (K2_BLK * 256)];

    // ---- resolve kmin: wave 0 reduces the 512 L2-hot keys, LDS-broadcast ----
    __shared__ unsigned long long skey;
    if (wid == 0) {
        unsigned long long key = ~0ULL;
        #pragma unroll
        for (int j = 0; j < K1_BLK / 64; ++j) {   // 8 strided loads per lane
            unsigned long long o = ws_keys[lane + j * 64];
            key = o < key ? o : key;
        }
        #pragma unroll
        for (int off = 32; off > 0; off >>= 1) {
            unsigned long long o = __shfl_down(key, off, 64);
            key = o < key ? o : key;
        }
        if (lane == 0) skey = key;
    }
    __syncthreads();
    const int kmin = (int)(skey & 0xFFFFFFFFu);
    const float* __restrict__ e = book + kmin * 64;   // L2-hot broadcast

    // ---- idx output: 32768 floats == float(kmin) (blocks 0..31) ----
    if (tid < NIDX / 4) {
        const float kf = (float)kmin;
        ((float4*)(out + NTOT))[tid] = make_float4(kf, kf, kf, kf);
    }

    // ---- z_q out [B,W,C,H] + fused loss over in [B,C,H,W], 4 float4/thread ----
    float part = 0.f;
    #pragma unroll
    for (int it = 0; it < K2_ITER; ++it) {
        const int i = tid + it * (K2_BLK * 256);       // float4 index
        // z_q: float offset o=4i -> value e[(o>>12)&63]
        const float ev = e[(i >> 10) & 63];
        ((float4*)out)[i] = make_float4(ev, ev, ev, ev);
        // loss: in float4 i covers w = (4i&63)..+3
        const float4 zz = z[it];
        const float4 ef = ((const float4*)e)[i & 15];
        const float d0 = zz.x - ef.x, d1 = zz.y - ef.y;
        const float d2 = zz.z - ef.z, d3 = zz.w - ef.w;
        part += d0 * d0 + d1 * d1 + d2 * d2 + d3 * d3;
    }
    #pragma unroll
    for (int off = 32; off > 0; off >>= 1) part += __shfl_down(part, off, 64);

    __shared__ float sp[4];
    if (lane == 0) sp[wid] = part;
    __syncthreads();
    if (threadIdx.x == 0)
        ws_part[blockIdx.x] = sp[0] + sp[1] + sp[2] + sp[3];   // plain store
}

__global__ __launch_bounds__(64) void k3_loss(const float* __restrict__ ws_part,
                                              float* __restrict__ out) {
    // single wave: sum 512 partials
    float s = 0.f;
    #pragma unroll
    for (int j = 0; j < K2_BLK / 64; ++j) s += ws_part[threadIdx.x + j * 64];
    #pragma unroll
    for (int off = 32; off > 0; off >>= 1) s += __shfl_down(s, off, 64);
    if (threadIdx.x == 0)
        out[NTOT + NIDX] = s * (1.25f / (float)NTOT);
}

extern "C" void kernel_launch(void* const* d_in, const int* in_sizes, int n_in,
                              void* d_out, int out_size, void* d_ws, size_t ws_size,
                              hipStream_t stream) {
    const float* in   = (const float*)d_in[0];   // [8,64,64,64] fp32
    const float* book = (const float*)d_in[1];   // [8192,64] fp32
    float* out = (float*)d_out;

    unsigned long long* ws_keys = (unsigned long long*)d_ws;
    float*              ws_part = (float*)((char*)d_ws + 4096);

    k1_argmin<<<K1_BLK, 256, 0, stream>>>(book, ws_keys);
    k2_main<<<K2_BLK, 256, 0, stream>>>(in, book, out, ws_keys, ws_part);
    k3_loss<<<1, 64, 0, stream>>>(ws_part, out);
}